// Round 1
// 31.683 us; speedup vs baseline: 1.6457x; 1.6457x over previous
//
#include <hip/hip_runtime.h>

// PropNet cost-volume via bf16 MFMA.
// N=2, C=256, H=W=96, max_distance=4 (window 9x9), num_class=124.
#define Nn 2
#define Cc 256
#define Hh 96
#define Ww 96
#define HW (Hh * Ww)
#define MD 4
#define NC 124
#define TH 4                    // dest tile rows
#define TWD 8                   // dest tile cols
#define NQ (TH * TWD)           // 32 dest pixels (MFMA M)
#define SH (TH + 2 * MD)        // 12 window rows
#define SWD (TWD + 2 * MD)      // 16 window cols
#define NS (SH * SWD)           // 192 src pixels (MFMA N)
#define BLK 256                 // 4 waves
#define KC 32                   // channels per K-chunk
#define NCH (Cc / KC)           // 8 chunks
#define NBW (Ww / TWD)          // 12
#define NBH (Hh / TH)           // 24
#define NBLK (Nn * NBH * NBW)   // 576 blocks (divisible by 8)
#define YROW 64                 // bytes per pixel row in a chunk (32 ch * 2B)
#define XOFF (NS * YROW)        // 12288: x region offset inside a buffer
#define BUFSZ (XOFF + NQ * YROW) // 14336 bytes per buffer
#define TBL (NQ * NC)           // 3968 table entries (15872B <= 2*BUFSZ)

typedef short short8 __attribute__((ext_vector_type(8)));
typedef float f32x4 __attribute__((ext_vector_type(4)));

// Monotone float -> uint mapping so unsigned min == float min.
__device__ __forceinline__ unsigned fmap(float f) {
    unsigned b = __float_as_uint(f);
    return (b & 0x80000000u) ? ~b : (b | 0x80000000u);
}
__device__ __forceinline__ float funmap(unsigned u) {
    unsigned b = (u & 0x80000000u) ? (u & 0x7fffffffu) : ~u;
    return __uint_as_float(b);
}
// XOR-swizzled byte offset of 16B slot `slot` in pixel-row `row`.
// Spreads the 4 slots of a 64B row over bank quads: 2-way on b128 (free).
__device__ __forceinline__ int swz(int row, int slot) {
    return row * YROW + ((slot ^ ((row >> 1) & 3)) << 4);
}

__global__ __launch_bounds__(BLK) void propnet_mfma(
    const float* __restrict__ x, const float* __restrict__ y,
    const int* __restrict__ labels, float* __restrict__ out)
{
    __shared__ __align__(16) unsigned char sbuf[2][BUFSZ];  // double-buffered bf16 staging
    __shared__ float y2s[NS];
    __shared__ float x2s[NQ];
    __shared__ int   labs[NS];
    unsigned* table = (unsigned*)&sbuf[0][0];  // aliased after the K-loop

    const int t = threadIdx.x;

    // XCD-aware bijective swizzle: contiguous 72-block chunk per XCD.
    const int orig = blockIdx.x;
    const int lin  = (orig & 7) * (NBLK / 8) + (orig >> 3);
    const int n    = lin / (NBH * NBW);
    const int rem  = lin - n * (NBH * NBW);
    const int h0   = (rem / NBW) * TH;
    const int w0   = (rem % NBW) * TWD;
    const size_t nb = (size_t)n * Cc * HW;

    if (t < NS) {
        y2s[t] = 0.f;
        const int sr = t >> 4, sc = t & 15;
        const int gh = h0 - MD + sr, gw = w0 - MD + sc;
        const bool ok = (gh >= 0) && (gh < Hh) && (gw >= 0) && (gw < Ww);
        labs[t] = ok ? labels[(size_t)n * HW + gh * Ww + gw] : -1;  // -1: excluded
    }
    if (t < NQ) x2s[t] = 0.f;

    // ---- staging descriptors (chunk-invariant) ----
    // y: 192 pix x 4 groups(8ch) = 768 tasks -> 3 per thread.
    const float* yptr[3]; int yoff[3]; int ypix[3];
#pragma unroll
    for (int i = 0; i < 3; ++i) {
        const int task = t + BLK * i;
        const int pix  = task % NS;
        const int grp  = task / NS;          // 0..3
        const int sr = pix >> 4, sc = pix & 15;
        const int gh = min(max(h0 - MD + sr, 0), Hh - 1);  // clamp; OOB excluded by labs
        const int gw = min(max(w0 - MD + sc, 0), Ww - 1);
        yptr[i] = y + nb + (size_t)(grp * 8) * HW + (size_t)gh * Ww + gw;
        yoff[i] = swz(pix, grp);
        ypix[i] = pix;
    }
    // x: 32 pix x 4 groups = 128 tasks -> threads 0..127 (waves 0,1).
    const float* xptr = x; int xoffw = 0, xpix = 0;
    if (t < 128) {
        xpix = t & 31;
        const int grp = t >> 5;
        const int qr = xpix >> 3, qc = xpix & 7;
        xptr = x + nb + (size_t)(grp * 8) * HW + (size_t)(h0 + qr) * Ww + (w0 + qc);
        xoffw = XOFF + swz(xpix, grp);
    }
    float ysq[3] = {0.f, 0.f, 0.f};
    float xsq = 0.f;

    // Load 8 strided channels, accumulate fp32 sq-norm, pack bf16 (truncate), ds_write_b128.
    auto stage = [&](unsigned char* bb, int c) {
        const size_t coff = (size_t)c * (KC * HW);
#pragma unroll
        for (int i = 0; i < 3; ++i) {
            const float* p = yptr[i] + coff;
            float v[8];
#pragma unroll
            for (int j = 0; j < 8; ++j) v[j] = p[(size_t)j * HW];
            unsigned pk[4];
#pragma unroll
            for (int j = 0; j < 4; ++j) {
                ysq[i] = fmaf(v[2*j],   v[2*j],   ysq[i]);
                ysq[i] = fmaf(v[2*j+1], v[2*j+1], ysq[i]);
                pk[j] = (__float_as_uint(v[2*j]) >> 16) |
                        (__float_as_uint(v[2*j+1]) & 0xffff0000u);
            }
            *(uint4*)(bb + yoff[i]) = make_uint4(pk[0], pk[1], pk[2], pk[3]);
        }
        if (t < 128) {
            const float* p = xptr + coff;
            float v[8];
#pragma unroll
            for (int j = 0; j < 8; ++j) v[j] = p[(size_t)j * HW];
            unsigned pk[4];
#pragma unroll
            for (int j = 0; j < 4; ++j) {
                xsq = fmaf(v[2*j],   v[2*j],   xsq);
                xsq = fmaf(v[2*j+1], v[2*j+1], xsq);
                pk[j] = (__float_as_uint(v[2*j]) >> 16) |
                        (__float_as_uint(v[2*j+1]) & 0xffff0000u);
            }
            *(uint4*)(bb + xoffw) = make_uint4(pk[0], pk[1], pk[2], pk[3]);
        }
    };

    // ---- MFMA fragment offsets (A: lane row=l&15 holds k-slot l>>4; B identical on y rows) ----
    const int lane = t & 63;
    const int wid  = t >> 6;          // wave -> src cols [wid*48, +48)
    const int l15  = lane & 15;
    const int lg   = lane >> 4;       // k-slot (8 ch)
    int aoff[2], boff[3];
#pragma unroll
    for (int mf = 0; mf < 2; ++mf) aoff[mf] = XOFF + swz(mf * 16 + l15, lg);
#pragma unroll
    for (int nf = 0; nf < 3; ++nf) boff[nf] = swz(wid * 48 + nf * 16 + l15, lg);

    f32x4 acc[2][3];
#pragma unroll
    for (int mf = 0; mf < 2; ++mf)
#pragma unroll
        for (int nf = 0; nf < 3; ++nf)
            acc[mf][nf] = (f32x4){0.f, 0.f, 0.f, 0.f};

    auto compute = [&](const unsigned char* bb) {
        short8 a[2], b[3];
#pragma unroll
        for (int mf = 0; mf < 2; ++mf) a[mf] = *(const short8*)(bb + aoff[mf]);
#pragma unroll
        for (int nf = 0; nf < 3; ++nf) b[nf] = *(const short8*)(bb + boff[nf]);
#pragma unroll
        for (int mf = 0; mf < 2; ++mf)
#pragma unroll
            for (int nf = 0; nf < 3; ++nf)
                acc[mf][nf] = __builtin_amdgcn_mfma_f32_16x16x32_bf16(
                    a[mf], b[nf], acc[mf][nf], 0, 0, 0);
    };

    // ---- K-loop: double-buffered chunks of 32 channels ----
    stage(sbuf[0], 0);
    __syncthreads();
    for (int cc = 0; cc < 4; ++cc) {
        stage(sbuf[1], 2 * cc + 1);    // fill buf1 while computing buf0
        compute(sbuf[0]);
        __syncthreads();
        if (cc < 3) stage(sbuf[0], 2 * cc + 2);
        compute(sbuf[1]);
        __syncthreads();
    }

    // ---- reduce sq-norms; init tables (staging buffers dead now) ----
#pragma unroll
    for (int i = 0; i < 3; ++i) atomicAdd(&y2s[ypix[i]], ysq[i]);
    if (t < 128) atomicAdd(&x2s[xpix], xsq);
    for (int i = t; i < TBL; i += BLK) table[i] = 0xBF800000u;  // fmap(1.0f)
    __syncthreads();

    // ---- epilogue: d -> sigmoid -> label-masked min ----
    // C layout: col(n) = l&15, row(m) = (l>>4)*4 + reg.
#pragma unroll
    for (int mf = 0; mf < 2; ++mf) {
#pragma unroll
        for (int nf = 0; nf < 3; ++nf) {
#pragma unroll
            for (int r = 0; r < 4; ++r) {
                const int q = mf * 16 + lg * 4 + r;       // dest pixel 0..31
                const int s = wid * 48 + nf * 16 + l15;   // src pixel 0..191
                const int qr = q >> 3, qc = q & 7;
                const int sr = s >> 4, sc = s & 15;
                const int di = sr - qr, dj = sc - qc;
                const int lab = labs[s];
                if (di >= 0 && di <= 2 * MD && dj >= 0 && dj <= 2 * MD &&
                    lab >= 0 && lab < NC) {
                    const float d  = x2s[q] + y2s[s] - 2.0f * acc[mf][nf][r];
                    const float sg = 1.0f / (1.0f + __expf(-d));
                    atomicMin(&table[q * NC + lab], fmap(fmaf(2.0f, sg, -1.0f)));
                }
            }
        }
    }
    __syncthreads();

    // ---- write out[n][class][h0+qr][w0+qc]; consecutive i -> consecutive qc ----
    const size_t ob = (size_t)n * NC * HW;
    for (int i = t; i < TBL; i += BLK) {
        const int g = i >> 5;        // class
        const int q = i & 31;        // dest pixel
        const int qr = q >> 3, qc = q & 7;
        out[ob + (size_t)g * HW + (size_t)(h0 + qr) * Ww + (w0 + qc)] =
            funmap(table[q * NC + g]);
    }
}

extern "C" void kernel_launch(void* const* d_in, const int* in_sizes, int n_in,
                              void* d_out, int out_size, void* d_ws, size_t ws_size,
                              hipStream_t stream) {
    const float* x      = (const float*)d_in[0];
    const float* y      = (const float*)d_in[1];
    const int*   labels = (const int*)d_in[2];
    float*       out    = (float*)d_out;
    (void)in_sizes; (void)n_in; (void)out_size; (void)d_ws; (void)ws_size;

    propnet_mfma<<<dim3(NBLK), dim3(BLK), 0, stream>>>(x, y, labels, out);
}